// Round 10
// baseline (83.163 us; speedup 1.0000x reference)
//
#include <hip/hip_runtime.h>

#define Q 4096
#define L 8192

// ---------------------------------------------------------------------------
// K1: score[l] = ctx[l].q — wave-per-row, no LDS, no barriers.
//     2048 blocks x 4 waves = 8192 waves, one row each.
// ---------------------------------------------------------------------------
__global__ __launch_bounds__(256) void score_kernel(
    const float* __restrict__ ctx, const float* __restrict__ qvec,
    float* __restrict__ score)
{
    const int lane = threadIdx.x & 63;
    const int w    = blockIdx.x * 4 + (threadIdx.x >> 6);   // row id 0..8191
    const float4* __restrict__ row = (const float4*)(ctx + (size_t)w * Q);
    const float4* __restrict__ qv  = (const float4*)qvec;

    float a0 = 0.f, a1 = 0.f, a2 = 0.f, a3 = 0.f;
    #pragma unroll
    for (int c = 0; c < 16; c += 4) {
        float4 x0 = row[(c + 0) * 64 + lane], y0 = qv[(c + 0) * 64 + lane];
        float4 x1 = row[(c + 1) * 64 + lane], y1 = qv[(c + 1) * 64 + lane];
        float4 x2 = row[(c + 2) * 64 + lane], y2 = qv[(c + 2) * 64 + lane];
        float4 x3 = row[(c + 3) * 64 + lane], y3 = qv[(c + 3) * 64 + lane];
        a0 = fmaf(x0.x, y0.x, a0); a0 = fmaf(x0.y, y0.y, a0);
        a0 = fmaf(x0.z, y0.z, a0); a0 = fmaf(x0.w, y0.w, a0);
        a1 = fmaf(x1.x, y1.x, a1); a1 = fmaf(x1.y, y1.y, a1);
        a1 = fmaf(x1.z, y1.z, a1); a1 = fmaf(x1.w, y1.w, a1);
        a2 = fmaf(x2.x, y2.x, a2); a2 = fmaf(x2.y, y2.y, a2);
        a2 = fmaf(x2.z, y2.z, a2); a2 = fmaf(x2.w, y2.w, a2);
        a3 = fmaf(x3.x, y3.x, a3); a3 = fmaf(x3.y, y3.y, a3);
        a3 = fmaf(x3.z, y3.z, a3); a3 = fmaf(x3.w, y3.w, a3);
    }
    float d = (a0 + a1) + (a2 + a3);
    #pragma unroll
    for (int off = 32; off > 0; off >>= 1) d += __shfl_down(d, off, 64);
    if (lane == 0) score[w] = d;
}

// ---------------------------------------------------------------------------
// K2: att = softmax(score). Single block.
// ---------------------------------------------------------------------------
__global__ __launch_bounds__(1024) void softmax_kernel(
    const float* __restrict__ score, float* __restrict__ att)
{
    __shared__ float redm[16];
    __shared__ float reds[16];
    const int tid  = threadIdx.x;
    const int lane = tid & 63;
    const int wid  = tid >> 6;

    float m = -3.4e38f;
    for (int i = tid; i < L; i += 1024) m = fmaxf(m, score[i]);
    #pragma unroll
    for (int off = 32; off > 0; off >>= 1) m = fmaxf(m, __shfl_down(m, off, 64));
    if (lane == 0) redm[wid] = m;
    __syncthreads();
    float M = redm[0];
    #pragma unroll
    for (int w = 1; w < 16; ++w) M = fmaxf(M, redm[w]);

    float s = 0.f;
    for (int i = tid; i < L; i += 1024) s += __expf(score[i] - M);
    #pragma unroll
    for (int off = 32; off > 0; off >>= 1) s += __shfl_down(s, off, 64);
    if (lane == 0) reds[wid] = s;
    __syncthreads();
    float Z = 0.f;
    #pragma unroll
    for (int w = 0; w < 16; ++w) Z += reds[w];
    const float inv = 1.0f / Z;

    for (int i = tid; i < L; i += 1024) att[i] = __expf(score[i] - M) * inv;
}

// ---------------------------------------------------------------------------
// K3: weighted-sum partials. 512 blocks = 4 col-chunks (256 float4 cols) x
//     128 row-chunks (64 rows). Thread owns one float4 column, sweeps 64
//     rows; one barrier (att stage).  ctx should be L3-resident.
// ---------------------------------------------------------------------------
__global__ __launch_bounds__(256) void wsum_kernel(
    const float* __restrict__ ctx, const float* __restrict__ att,
    float* __restrict__ partial)
{
    __shared__ float att_s[64];
    const int cc  = blockIdx.x & 3;          // col chunk 0..3
    const int rc  = blockIdx.x >> 2;         // row chunk 0..127
    const int tid = threadIdx.x;
    const int col = cc * 256 + tid;          // float4 column

    if (tid < 64) att_s[tid] = att[rc * 64 + tid];
    __syncthreads();

    const float4* __restrict__ cb = (const float4*)ctx;
    const int r0 = rc * 64;
    float4 acc = make_float4(0.f, 0.f, 0.f, 0.f);
    #pragma unroll 8
    for (int r = 0; r < 64; ++r) {
        const float a = att_s[r];
        float4 v = cb[(size_t)(r0 + r) * (Q / 4) + col];
        acc.x = fmaf(a, v.x, acc.x);
        acc.y = fmaf(a, v.y, acc.y);
        acc.z = fmaf(a, v.z, acc.z);
        acc.w = fmaf(a, v.w, acc.w);
    }
    ((float4*)partial)[(size_t)rc * (Q / 4) + col] = acc;
}

// ---------------------------------------------------------------------------
// K4: s_t[j] = sum over 128 partial rows. 4 blocks x 256 threads.
// ---------------------------------------------------------------------------
__global__ __launch_bounds__(256) void reduce_kernel(
    const float* __restrict__ partial, float* __restrict__ s_t)
{
    const int c4 = blockIdx.x * 256 + threadIdx.x;   // float4 column
    const float4* __restrict__ p = (const float4*)partial;
    float4 acc = make_float4(0.f, 0.f, 0.f, 0.f);
    #pragma unroll 8
    for (int b = 0; b < 128; ++b) {
        float4 v = p[(size_t)b * (Q / 4) + c4];
        acc.x += v.x; acc.y += v.y; acc.z += v.z; acc.w += v.w;
    }
    ((float4*)s_t)[c4] = acc;
}

// ---------------------------------------------------------------------------
// K5: out[i] = Kw[i,0:Q].q + Kw[i,Q:2Q].s_t — wave-per-row over the full
//     32 KB Kw row, contiguous stream, no LDS, no barriers.
//     1024 blocks x 4 waves = 4096 waves, one output row each.
// ---------------------------------------------------------------------------
__global__ __launch_bounds__(256) void out_kernel(
    const float* __restrict__ Kw, const float* __restrict__ qvec,
    const float* __restrict__ s_t, float* __restrict__ out)
{
    const int lane = threadIdx.x & 63;
    const int i    = blockIdx.x * 4 + (threadIdx.x >> 6);   // 0..4095
    const float4* __restrict__ row = (const float4*)(Kw + (size_t)i * (2 * Q));
    const float4* __restrict__ qv  = (const float4*)qvec;
    const float4* __restrict__ sv  = (const float4*)s_t;

    float a0 = 0.f, a1 = 0.f, a2 = 0.f, a3 = 0.f;
    #pragma unroll
    for (int c = 0; c < 16; c += 4) {
        float4 x0 = row[(c + 0) * 64 + lane], y0 = qv[(c + 0) * 64 + lane];
        float4 x1 = row[(c + 1) * 64 + lane], y1 = qv[(c + 1) * 64 + lane];
        float4 x2 = row[(c + 2) * 64 + lane], y2 = qv[(c + 2) * 64 + lane];
        float4 x3 = row[(c + 3) * 64 + lane], y3 = qv[(c + 3) * 64 + lane];
        a0 = fmaf(x0.x, y0.x, a0); a0 = fmaf(x0.y, y0.y, a0);
        a0 = fmaf(x0.z, y0.z, a0); a0 = fmaf(x0.w, y0.w, a0);
        a1 = fmaf(x1.x, y1.x, a1); a1 = fmaf(x1.y, y1.y, a1);
        a1 = fmaf(x1.z, y1.z, a1); a1 = fmaf(x1.w, y1.w, a1);
        a2 = fmaf(x2.x, y2.x, a2); a2 = fmaf(x2.y, y2.y, a2);
        a2 = fmaf(x2.z, y2.z, a2); a2 = fmaf(x2.w, y2.w, a2);
        a3 = fmaf(x3.x, y3.x, a3); a3 = fmaf(x3.y, y3.y, a3);
        a3 = fmaf(x3.z, y3.z, a3); a3 = fmaf(x3.w, y3.w, a3);
    }
    #pragma unroll
    for (int c = 0; c < 16; c += 4) {
        float4 x0 = row[(16 + c + 0) * 64 + lane], y0 = sv[(c + 0) * 64 + lane];
        float4 x1 = row[(16 + c + 1) * 64 + lane], y1 = sv[(c + 1) * 64 + lane];
        float4 x2 = row[(16 + c + 2) * 64 + lane], y2 = sv[(c + 2) * 64 + lane];
        float4 x3 = row[(16 + c + 3) * 64 + lane], y3 = sv[(c + 3) * 64 + lane];
        a0 = fmaf(x0.x, y0.x, a0); a0 = fmaf(x0.y, y0.y, a0);
        a0 = fmaf(x0.z, y0.z, a0); a0 = fmaf(x0.w, y0.w, a0);
        a1 = fmaf(x1.x, y1.x, a1); a1 = fmaf(x1.y, y1.y, a1);
        a1 = fmaf(x1.z, y1.z, a1); a1 = fmaf(x1.w, y1.w, a1);
        a2 = fmaf(x2.x, y2.x, a2); a2 = fmaf(x2.y, y2.y, a2);
        a2 = fmaf(x2.z, y2.z, a2); a2 = fmaf(x2.w, y2.w, a2);
        a3 = fmaf(x3.x, y3.x, a3); a3 = fmaf(x3.y, y3.y, a3);
        a3 = fmaf(x3.z, y3.z, a3); a3 = fmaf(x3.w, y3.w, a3);
    }
    float d = (a0 + a1) + (a2 + a3);
    #pragma unroll
    for (int off = 32; off > 0; off >>= 1) d += __shfl_down(d, off, 64);
    if (lane == 0) out[i] = d;
}

// ---------------------------------------------------------------------------
extern "C" void kernel_launch(void* const* d_in, const int* in_sizes, int n_in,
                              void* d_out, int out_size, void* d_ws, size_t ws_size,
                              hipStream_t stream)
{
    const float* query = (const float*)d_in[0];   // [Q]
    const float* ctx   = (const float*)d_in[1];   // [L, Q]
    const float* Kw    = (const float*)d_in[2];   // [Q, 2Q]
    float* out = (float*)d_out;                   // [Q]

    // workspace layout (floats)
    float* ws      = (float*)d_ws;
    float* score   = ws;                          // 8192
    float* att     = ws + L;                      // 8192
    float* s_t     = ws + 2 * L;                  // 4096
    float* partial = ws + 2 * L + Q;              // 128*4096 = 2 MiB

    score_kernel<<<2048, 256, 0, stream>>>(ctx, query, score);
    softmax_kernel<<<1, 1024, 0, stream>>>(score, att);
    wsum_kernel<<<512, 256, 0, stream>>>(ctx, att, partial);
    reduce_kernel<<<4, 256, 0, stream>>>(partial, s_t);
    out_kernel<<<1024, 256, 0, stream>>>(Kw, query, s_t, out);
}